// Round 1
// baseline (3945.258 us; speedup 1.0000x reference)
//
#include <hip/hip_runtime.h>
#include <hip/hip_bf16.h>

#define HD 64
#define TKEY 64
#define NQT 16   // float4s per head-dim vector (64 floats)

// ---------------------------------------------------------------------------
// Block attention for one dilation. 1 thread = 1 dilated query row.
// Accumulates num[pos] += exp(m)*o_unnorm (== de * a), wsum[pos] += exp(m)*l (== de).
// ---------------------------------------------------------------------------
__global__ __launch_bounds__(256)
void attn_dil_kernel(const float* __restrict__ Q, const float* __restrict__ K,
                     const float* __restrict__ V, float* __restrict__ num,
                     float* __restrict__ wsum, int d, int L, int bs, int first)
{
    const int Ld = L / d;
    const int wgs_per_bh = Ld >> 8;                 // 256 rows per workgroup
    const int bh = blockIdx.x / wgs_per_bh;
    const int wg_row = (blockIdx.x % wgs_per_bh) << 8;
    const int tid = threadIdx.x;
    const int r = wg_row + tid;                     // dilated row index
    const int block_start = (wg_row / bs) * bs;     // attention block start (dilated)

    __shared__ float kls[TKEY][HD + 4];             // +4 pad: kills 16-way write conflicts
    __shared__ float vls[TKEY][HD + 4];

    const size_t qoff = ((size_t)bh * L + (size_t)r * d) * HD;
    float4 q4[NQT];
#pragma unroll
    for (int i = 0; i < NQT; ++i) q4[i] = ((const float4*)(Q + qoff))[i];

    float4 o4[NQT];
#pragma unroll
    for (int i = 0; i < NQT; ++i) o4[i] = make_float4(0.f, 0.f, 0.f, 0.f);
    float m = -1e30f, l = 0.f;

    const int j    = tid >> 2;                      // key within tile (0..63)
    const int part = tid & 3;

    for (int kt = 0; kt < bs; kt += TKEY) {
        // ---- stage K/V tile (coalesced: 4 lanes cover one 256B key row) ----
        const size_t goff = ((size_t)bh * L + (size_t)(block_start + kt + j) * d) * HD;
        const float4* kg = (const float4*)(K + goff);
        const float4* vg = (const float4*)(V + goff);
        float4* kd = (float4*)(&kls[j][0]);
        float4* vd = (float4*)(&vls[j][0]);
#pragma unroll
        for (int i = 0; i < 4; ++i) {
            kd[part + i * 4] = kg[part + i * 4];
            vd[part + i * 4] = vg[part + i * 4];
        }
        __syncthreads();

        // ---- process 64 keys, 16 at a time (one softmax rescale per 16) ----
#pragma unroll
        for (int jt = 0; jt < TKEY; jt += 16) {
            float s[16];
#pragma unroll
            for (int jj = 0; jj < 16; ++jj) {
                const float4* kk4 = (const float4*)(&kls[jt + jj][0]); // broadcast reads
                float a0 = 0.f, a1 = 0.f, a2 = 0.f, a3 = 0.f;
#pragma unroll
                for (int e = 0; e < NQT; e += 4) {
                    float4 qa = q4[e + 0], ka = kk4[e + 0];
                    a0 += qa.x * ka.x + qa.y * ka.y + qa.z * ka.z + qa.w * ka.w;
                    float4 qb = q4[e + 1], kb = kk4[e + 1];
                    a1 += qb.x * kb.x + qb.y * kb.y + qb.z * kb.z + qb.w * kb.w;
                    float4 qc = q4[e + 2], kc = kk4[e + 2];
                    a2 += qc.x * kc.x + qc.y * kc.y + qc.z * kc.z + qc.w * kc.w;
                    float4 qd = q4[e + 3], kd2 = kk4[e + 3];
                    a3 += qd.x * kd2.x + qd.y * kd2.y + qd.z * kd2.z + qd.w * kd2.w;
                }
                s[jj] = (a0 + a1 + a2 + a3) * 0.125f;   // 1/sqrt(64)
            }
            float tmax = s[0];
#pragma unroll
            for (int jj = 1; jj < 16; ++jj) tmax = fmaxf(tmax, s[jj]);
            const float mnew = fmaxf(m, tmax);
            const float corr = __expf(m - mnew);        // first tile: exp(-huge)=0
            l *= corr;
#pragma unroll
            for (int i = 0; i < NQT; ++i) {
                o4[i].x *= corr; o4[i].y *= corr; o4[i].z *= corr; o4[i].w *= corr;
            }
#pragma unroll
            for (int jj = 0; jj < 16; ++jj) {
                const float p = __expf(s[jj] - mnew);
                l += p;
                const float4* vv = (const float4*)(&vls[jt + jj][0]); // broadcast
#pragma unroll
                for (int i = 0; i < NQT; ++i) {
                    float4 v4 = vv[i];
                    o4[i].x += p * v4.x; o4[i].y += p * v4.y;
                    o4[i].z += p * v4.z; o4[i].w += p * v4.w;
                }
            }
            m = mnew;
        }
        __syncthreads();
    }

    // ---- epilogue: de*a = exp(m)*o_unnorm ; de = exp(m)*l ----
    const float em = __expf(m);
    float* np_ = num + qoff;
    const size_t widx = (size_t)bh * L + (size_t)r * d;
    if (first) {
#pragma unroll
        for (int i = 0; i < NQT; ++i) {
            float4 o = o4[i];
            ((float4*)np_)[i] = make_float4(o.x * em, o.y * em, o.z * em, o.w * em);
        }
        wsum[widx] = em * l;
    } else {
#pragma unroll
        for (int i = 0; i < NQT; ++i) {
            float4 cur = ((float4*)np_)[i];
            float4 o = o4[i];
            ((float4*)np_)[i] = make_float4(cur.x + o.x * em, cur.y + o.y * em,
                                            cur.z + o.z * em, cur.w + o.w * em);
        }
        wsum[widx] += em * l;
    }
}

// ---------------------------------------------------------------------------
// out(b,L,512) = [num/wsum, transposed (b,h,L,hd)->(b*L, h*hd)] @ Wo^T + bo
// fp32 tiled GEMM, 64x64 tile, BK=16, 256 threads, 4x4 acc per thread.
// ---------------------------------------------------------------------------
__global__ __launch_bounds__(256)
void proj_kernel(const float* __restrict__ num, const float* __restrict__ wsum,
                 const float* __restrict__ Wo, const float* __restrict__ bo,
                 float* __restrict__ out)
{
    const int L = 4096;
    const int HN = 512;
    const int nbn = HN / 64;                 // 8
    const int bm = (int)(blockIdx.x / nbn) * 64;
    const int bn = (int)(blockIdx.x % nbn) * 64;
    const int tid = threadIdx.x;

    __shared__ float As[16][64];
    __shared__ float Bs[16][64 + 4];

    const int arow  = tid >> 2;              // 0..63 (row within tile)
    const int acol4 = tid & 3;               // float4 within 16-wide k slab
    const int rm = bm + arow;
    const int bi = rm >> 12;                 // L = 4096
    const int li = rm & 4095;

    const int tm = tid >> 4;                 // 0..15
    const int tn = tid & 15;

    float acc[4][4] = {};

    for (int bk = 0; bk < HN; bk += 16) {
        // A tile: A[rm][bk+kk] = num[bi][h][li][c&63] / wsum[bi][h][li]
        {
            const int h = bk >> 6;
            const size_t rowbase = (size_t)(bi * 8 + h) * L + li;
            const float winv = 1.0f / wsum[rowbase];
            const float4 a4 =
                ((const float4*)(num + rowbase * HD))[((bk & 63) >> 2) + acol4];
            As[acol4 * 4 + 0][arow] = a4.x * winv;
            As[acol4 * 4 + 1][arow] = a4.y * winv;
            As[acol4 * 4 + 2][arow] = a4.z * winv;
            As[acol4 * 4 + 3][arow] = a4.w * winv;
        }
        // B tile: Bs[kk][n] = Wo[(bn+n)*HN + bk+kk]
        {
            const int nb_ = tid >> 2;
            const int ch  = tid & 3;
            const float4 w4 =
                *(const float4*)(Wo + (size_t)(bn + nb_) * HN + bk + ch * 4);
            Bs[ch * 4 + 0][nb_] = w4.x;
            Bs[ch * 4 + 1][nb_] = w4.y;
            Bs[ch * 4 + 2][nb_] = w4.z;
            Bs[ch * 4 + 3][nb_] = w4.w;
        }
        __syncthreads();
#pragma unroll
        for (int kk = 0; kk < 16; ++kk) {
            float a[4], b[4];
#pragma unroll
            for (int i = 0; i < 4; ++i) a[i] = As[kk][tm * 4 + i];
#pragma unroll
            for (int jj = 0; jj < 4; ++jj) b[jj] = Bs[kk][tn * 4 + jj];
#pragma unroll
            for (int i = 0; i < 4; ++i)
#pragma unroll
                for (int jj = 0; jj < 4; ++jj)
                    acc[i][jj] += a[i] * b[jj];
        }
        __syncthreads();
    }

#pragma unroll
    for (int i = 0; i < 4; ++i) {
        const int orow = bm + tm * 4 + i;
        const float4 bias = *(const float4*)(bo + bn + tn * 4);
        float4 res = make_float4(acc[i][0] + bias.x, acc[i][1] + bias.y,
                                 acc[i][2] + bias.z, acc[i][3] + bias.w);
        *(float4*)(out + (size_t)orow * HN + bn + tn * 4) = res;
    }
}

extern "C" void kernel_launch(void* const* d_in, const int* in_sizes, int n_in,
                              void* d_out, int out_size, void* d_ws, size_t ws_size,
                              hipStream_t stream)
{
    const float* Q  = (const float*)d_in[0];
    const float* K  = (const float*)d_in[1];
    const float* V  = (const float*)d_in[2];
    const float* Wo = (const float*)d_in[3];
    const float* bo = (const float*)d_in[4];
    float* out = (float*)d_out;

    const int B = 4, H = 8, L = 4096;
    float* num  = (float*)d_ws;                                  // (B,H,L,64) f32 = 33.5 MB
    float* wsum = num + (size_t)B * H * L * HD;                  // (B,H,L)    f32 = 0.5 MB

    const int dil[4] = {1, 2, 4, 8};
    for (int i = 0; i < 4; ++i) {
        const int d  = dil[i];
        const int Ld = L / d;
        const int bs = (Ld < 1024) ? Ld : 1024;
        dim3 grid(B * H * (Ld / 256));
        hipLaunchKernelGGL(attn_dil_kernel, grid, dim3(256), 0, stream,
                           Q, K, V, num, wsum, d, L, bs, (i == 0) ? 1 : 0);
    }

    dim3 g2((B * L / 64) * (512 / 64));   // 2048 blocks
    hipLaunchKernelGGL(proj_kernel, g2, dim3(256), 0, stream, num, wsum, Wo, bo, out);
}

// Round 2
// 339.661 us; speedup vs baseline: 11.6153x; 11.6153x over previous
//
#include <hip/hip_runtime.h>
#include <hip/hip_bf16.h>

typedef __attribute__((ext_vector_type(8))) short bf16x8;
typedef __attribute__((ext_vector_type(4))) float f32x4;

union F8 { bf16x8 v; unsigned u[4]; unsigned short s[8]; };

__device__ __forceinline__ unsigned pk2(float a, float b) {
    __hip_bfloat162 t = __float22bfloat162_rn(make_float2(a, b));
    unsigned r; __builtin_memcpy(&r, &t, 4); return r;
}
__device__ __forceinline__ unsigned short f2bf(float a) {
    __hip_bfloat16 t = __float2bfloat16(a);
    unsigned short r; __builtin_memcpy(&r, &t, 2); return r;
}
__device__ __forceinline__ float bf2f(unsigned short s) {
    unsigned u = ((unsigned)s) << 16; float f; __builtin_memcpy(&f, &u, 4); return f;
}
#define SWZ(byteoff, row) ((byteoff) ^ (((row) & 7) << 4))
#define MFMA(a, b, c) __builtin_amdgcn_mfma_f32_16x16x32_bf16((a), (b), (c), 0, 0, 0)

// ---------------------------------------------------------------------------
// Flash attention for one dilation. 256 thr = 4 waves, 32 q-rows per wave.
// num (B,L,H*HD) += de*a (transposed for proj); wsum (B,L,H) += de.
// ---------------------------------------------------------------------------
__global__ __launch_bounds__(256)
void attn_mfma(const float* __restrict__ Q, const float* __restrict__ K,
               const float* __restrict__ V, float* __restrict__ num,
               float* __restrict__ wsum, int d, int bs, int npb, int first)
{
    const int L = 4096;
    const int bh = blockIdx.x / npb;
    const int qt = blockIdx.x % npb;
    const int b = bh >> 3, h = bh & 7;
    const int tid = threadIdx.x;
    const int w = tid >> 6, lane = tid & 63;
    const int g = lane >> 4, c = lane & 15;
    const int bstart = ((qt * 128) / bs) * bs;
    const int qrow0 = qt * 128 + w * 32;

    __shared__ __align__(16) char smem[32 * 1024];
    char* const Kls = smem;                       // [64][64] bf16, swizzled
    char* const Vls = smem + 8192;                // [64 dim][64 key] bf16 (transposed)
    char* const Pls = smem + 16384 + w * 4096;    // per-wave [32][64] bf16

    const size_t base = (size_t)bh * L * 64;

    // Q fragments, scale 1/sqrt(64) folded into the convert
    bf16x8 qf[2][2];
#pragma unroll
    for (int qi = 0; qi < 2; ++qi) {
        const float* qp = Q + base + (size_t)(qrow0 + qi * 16 + c) * d * 64 + g * 8;
#pragma unroll
        for (int s = 0; s < 2; ++s) {
            float4 x = ((const float4*)(qp + s * 32))[0];
            float4 y = ((const float4*)(qp + s * 32))[1];
            F8 f;
            f.u[0] = pk2(x.x * 0.125f, x.y * 0.125f);
            f.u[1] = pk2(x.z * 0.125f, x.w * 0.125f);
            f.u[2] = pk2(y.x * 0.125f, y.y * 0.125f);
            f.u[3] = pk2(y.z * 0.125f, y.w * 0.125f);
            qf[qi][s] = f.v;
        }
    }

    f32x4 o[2][4];
#pragma unroll
    for (int qi = 0; qi < 2; ++qi)
#pragma unroll
        for (int dj = 0; dj < 4; ++dj) o[qi][dj] = (f32x4){0.f, 0.f, 0.f, 0.f};
    float mrow[2][4], lrow[2][4];
#pragma unroll
    for (int qi = 0; qi < 2; ++qi)
#pragma unroll
        for (int r = 0; r < 4; ++r) { mrow[qi][r] = -1e30f; lrow[qi][r] = 0.f; }

    const int krow = tid >> 2, kpart = tid & 3;

    for (int kt = 0; kt < bs; kt += 64) {
        // ---- stage K tile (64 keys x 64 dims), bf16, XOR-swizzled ----
        {
            const float* kp = K + base + (size_t)(bstart + kt + krow) * d * 64 + kpart * 16;
#pragma unroll
            for (int i = 0; i < 4; ++i) {
                float4 kx = ((const float4*)kp)[i];
                uint2 wv; wv.x = pk2(kx.x, kx.y); wv.y = pk2(kx.z, kx.w);
                *(uint2*)(Kls + SWZ(krow * 128 + kpart * 32 + i * 8, krow)) = wv;
            }
        }
        // ---- stage V transposed: lane = dim, wave w covers 16 keys ----
        {
            const float* vp = V + base + (size_t)(bstart + kt + w * 16) * d * 64 + lane;
            const size_t stride = (size_t)d * 64;
            float vv[16];
#pragma unroll
            for (int kk = 0; kk < 16; ++kk) vv[kk] = vp[kk * stride];
            F8 f0, f1;
#pragma unroll
            for (int i = 0; i < 4; ++i) {
                f0.u[i] = pk2(vv[2 * i], vv[2 * i + 1]);
                f1.u[i] = pk2(vv[8 + 2 * i], vv[9 + 2 * i]);
            }
            *(bf16x8*)(Vls + SWZ(lane * 128 + w * 32, lane)) = f0.v;
            *(bf16x8*)(Vls + SWZ(lane * 128 + w * 32 + 16, lane)) = f1.v;
        }
        __syncthreads();

        // ---- S = Q K^T : 2 qi x 4 kj tiles, 2 k-slices each ----
        f32x4 st[2][4];
#pragma unroll
        for (int qi = 0; qi < 2; ++qi)
#pragma unroll
            for (int kj = 0; kj < 4; ++kj) {
                f32x4 acc = (f32x4){0.f, 0.f, 0.f, 0.f};
#pragma unroll
                for (int s = 0; s < 2; ++s) {
                    const int row = 16 * kj + c;
                    bf16x8 kf = *(const bf16x8*)(Kls + SWZ(row * 128 + s * 64 + g * 16, row));
                    acc = MFMA(qf[qi][s], kf, acc);
                }
                st[qi][kj] = acc;
            }

        // ---- online softmax (16-wide shfl reduces) + P -> LDS bf16 ----
#pragma unroll
        for (int qi = 0; qi < 2; ++qi) {
            float corr[4];
#pragma unroll
            for (int r = 0; r < 4; ++r) {
                float t = fmaxf(fmaxf(st[qi][0][r], st[qi][1][r]),
                                fmaxf(st[qi][2][r], st[qi][3][r]));
#pragma unroll
                for (int mk = 1; mk < 16; mk <<= 1) t = fmaxf(t, __shfl_xor(t, mk));
                const float mnew = fmaxf(mrow[qi][r], t);
                corr[r] = __expf(mrow[qi][r] - mnew);
                mrow[qi][r] = mnew;
            }
#pragma unroll
            for (int r = 0; r < 4; ++r) {
                float rs = 0.f;
#pragma unroll
                for (int kj = 0; kj < 4; ++kj) {
                    const float p = __expf(st[qi][kj][r] - mrow[qi][r]);
                    st[qi][kj][r] = p;
                    rs += p;
                }
#pragma unroll
                for (int mk = 1; mk < 16; mk <<= 1) rs += __shfl_xor(rs, mk);
                lrow[qi][r] = lrow[qi][r] * corr[r] + rs;
            }
#pragma unroll
            for (int dj = 0; dj < 4; ++dj) {
                f32x4 t = o[qi][dj];
                t[0] *= corr[0]; t[1] *= corr[1]; t[2] *= corr[2]; t[3] *= corr[3];
                o[qi][dj] = t;
            }
#pragma unroll
            for (int kj = 0; kj < 4; ++kj)
#pragma unroll
                for (int r = 0; r < 4; ++r) {
                    const int prow = 16 * qi + 4 * g + r;
                    *(unsigned short*)(Pls + SWZ(prow * 128 + (16 * kj + c) * 2, prow))
                        = f2bf(st[qi][kj][r]);
                }
        }

        // ---- O += P V ----
#pragma unroll
        for (int qi = 0; qi < 2; ++qi)
#pragma unroll
            for (int s = 0; s < 2; ++s) {
                const int prow = 16 * qi + c;
                bf16x8 pf = *(const bf16x8*)(Pls + SWZ(prow * 128 + s * 64 + g * 16, prow));
#pragma unroll
                for (int dj = 0; dj < 4; ++dj) {
                    const int vrow = 16 * dj + c;
                    bf16x8 vf = *(const bf16x8*)(Vls + SWZ(vrow * 128 + s * 64 + g * 16, vrow));
                    o[qi][dj] = MFMA(pf, vf, o[qi][dj]);
                }
            }
        __syncthreads();
    }

    // ---- epilogue: num += exp(m)*O_unnorm (transposed layout), wsum += exp(m)*l ----
#pragma unroll
    for (int qi = 0; qi < 2; ++qi)
#pragma unroll
        for (int r = 0; r < 4; ++r) {
            const int q = qrow0 + qi * 16 + 4 * g + r;
            const float em = __expf(mrow[qi][r]);
            float* np = num + ((size_t)b * L + (size_t)q * d) * 512 + h * 64 + c;
            if (first) {
#pragma unroll
                for (int dj = 0; dj < 4; ++dj) np[dj * 16] = o[qi][dj][r] * em;
                if (c == 0) wsum[((size_t)b * L + (size_t)q * d) * 8 + h] = em * lrow[qi][r];
            } else {
#pragma unroll
                for (int dj = 0; dj < 4; ++dj) np[dj * 16] += o[qi][dj][r] * em;
                if (c == 0) wsum[((size_t)b * L + (size_t)q * d) * 8 + h] += em * lrow[qi][r];
            }
        }
}

// ---------------------------------------------------------------------------
// out(16384,512) = [num/wsum] @ Wo^T + bo.  128x128 tile, BK=64, 4 waves.
// Split-precision bf16 (hi+lo): 3 MFMAs per product, error ~= fp32.
// ---------------------------------------------------------------------------
__global__ __launch_bounds__(256)
void proj_mfma(const float* __restrict__ num, const float* __restrict__ wsum,
               const float* __restrict__ Wo, const float* __restrict__ bo,
               float* __restrict__ out)
{
    __shared__ __align__(16) char smem[64 * 1024];
    char* const Ah = smem;
    char* const Al = smem + 16384;
    char* const Bh = smem + 32768;
    char* const Bl = smem + 49152;

    const int tid = threadIdx.x;
    const int w = tid >> 6, lane = tid & 63, g = lane >> 4, c = lane & 15;
    const int wm = (w >> 1) * 64, wn = (w & 1) * 64;
    const int bm = (int)(blockIdx.x >> 2) * 128, bn = (int)(blockIdx.x & 3) * 128;
    const int srow = tid >> 1, koff = (tid & 1) * 32;

    f32x4 acc[4][4];
#pragma unroll
    for (int mi = 0; mi < 4; ++mi)
#pragma unroll
        for (int ni = 0; ni < 4; ++ni) acc[mi][ni] = (f32x4){0.f, 0.f, 0.f, 0.f};

    for (int bk = 0; bk < 512; bk += 64) {
        {
            const float* ap = num + (size_t)(bm + srow) * 512 + bk + koff;
            const float winv = 1.0f / wsum[(size_t)(bm + srow) * 8 + (bk >> 6)];
#pragma unroll
            for (int i = 0; i < 8; ++i) {
                float4 a4 = ((const float4*)ap)[i];
                float v0 = a4.x * winv, v1 = a4.y * winv, v2 = a4.z * winv, v3 = a4.w * winv;
                unsigned short h0 = f2bf(v0), h1 = f2bf(v1), h2 = f2bf(v2), h3 = f2bf(v3);
                uint2 hi; hi.x = h0 | ((unsigned)h1 << 16); hi.y = h2 | ((unsigned)h3 << 16);
                uint2 lo;
                lo.x = f2bf(v0 - bf2f(h0)) | ((unsigned)f2bf(v1 - bf2f(h1)) << 16);
                lo.y = f2bf(v2 - bf2f(h2)) | ((unsigned)f2bf(v3 - bf2f(h3)) << 16);
                const int off = SWZ(srow * 128 + koff * 2 + i * 8, srow);
                *(uint2*)(Ah + off) = hi;
                *(uint2*)(Al + off) = lo;
            }
            const float* bp = Wo + (size_t)(bn + srow) * 512 + bk + koff;
#pragma unroll
            for (int i = 0; i < 8; ++i) {
                float4 a4 = ((const float4*)bp)[i];
                unsigned short h0 = f2bf(a4.x), h1 = f2bf(a4.y), h2 = f2bf(a4.z), h3 = f2bf(a4.w);
                uint2 hi; hi.x = h0 | ((unsigned)h1 << 16); hi.y = h2 | ((unsigned)h3 << 16);
                uint2 lo;
                lo.x = f2bf(a4.x - bf2f(h0)) | ((unsigned)f2bf(a4.y - bf2f(h1)) << 16);
                lo.y = f2bf(a4.z - bf2f(h2)) | ((unsigned)f2bf(a4.w - bf2f(h3)) << 16);
                const int off = SWZ(srow * 128 + koff * 2 + i * 8, srow);
                *(uint2*)(Bh + off) = hi;
                *(uint2*)(Bl + off) = lo;
            }
        }
        __syncthreads();
#pragma unroll
        for (int s = 0; s < 2; ++s) {
            bf16x8 ah[4], al[4], bh[4], bl[4];
#pragma unroll
            for (int mi = 0; mi < 4; ++mi) {
                const int row = wm + 16 * mi + c;
                const int off = SWZ(row * 128 + s * 64 + g * 16, row);
                ah[mi] = *(const bf16x8*)(Ah + off);
                al[mi] = *(const bf16x8*)(Al + off);
            }
#pragma unroll
            for (int ni = 0; ni < 4; ++ni) {
                const int row = wn + 16 * ni + c;
                const int off = SWZ(row * 128 + s * 64 + g * 16, row);
                bh[ni] = *(const bf16x8*)(Bh + off);
                bl[ni] = *(const bf16x8*)(Bl + off);
            }
#pragma unroll
            for (int mi = 0; mi < 4; ++mi)
#pragma unroll
                for (int ni = 0; ni < 4; ++ni) {
                    acc[mi][ni] = MFMA(ah[mi], bh[ni], acc[mi][ni]);
                    acc[mi][ni] = MFMA(ah[mi], bl[ni], acc[mi][ni]);
                    acc[mi][ni] = MFMA(al[mi], bh[ni], acc[mi][ni]);
                }
        }
        __syncthreads();
    }

    float bias[4];
#pragma unroll
    for (int ni = 0; ni < 4; ++ni) bias[ni] = bo[bn + wn + 16 * ni + c];
#pragma unroll
    for (int mi = 0; mi < 4; ++mi)
#pragma unroll
        for (int r = 0; r < 4; ++r) {
            float* op = out + (size_t)(bm + wm + 16 * mi + 4 * g + r) * 512 + bn + wn + c;
#pragma unroll
            for (int ni = 0; ni < 4; ++ni)
                op[ni * 16] = acc[mi][ni][r] + bias[ni];
        }
}

extern "C" void kernel_launch(void* const* d_in, const int* in_sizes, int n_in,
                              void* d_out, int out_size, void* d_ws, size_t ws_size,
                              hipStream_t stream)
{
    const float* Q  = (const float*)d_in[0];
    const float* K  = (const float*)d_in[1];
    const float* V  = (const float*)d_in[2];
    const float* Wo = (const float*)d_in[3];
    const float* bo = (const float*)d_in[4];
    float* out = (float*)d_out;

    float* num  = (float*)d_ws;                          // (B, L, H*HD) f32 = 33.5 MB
    float* wsum = num + (size_t)4 * 4096 * 512;          // (B, L, H)    f32 = 0.5 MB

    const int dil[4] = {1, 2, 4, 8};
    for (int i = 0; i < 4; ++i) {
        const int d  = dil[i];
        const int Ld = 4096 / d;
        const int bs = (Ld < 1024) ? Ld : 1024;
        const int npb = Ld / 128;
        hipLaunchKernelGGL(attn_mfma, dim3(32 * npb), dim3(256), 0, stream,
                           Q, K, V, num, wsum, d, bs, npb, (i == 0) ? 1 : 0);
    }
    hipLaunchKernelGGL(proj_mfma, dim3(512), dim3(256), 0, stream,
                       num, wsum, Wo, bo, out);
}